// Round 1
// baseline (321.998 us; speedup 1.0000x reference)
//
#include <hip/hip_runtime.h>
#include <math.h>

// LiquidEchoHead: per-row interference -> alpha -> oscillator evolution.
// One block per row (256 threads). x_real/x_imag held in registers across
// both phases so each x element is fetched from HBM exactly once.
// Identity used: cos(a)cos(b)-sin(a)sin(b)=cos(a+b), cos(a)sin(b)+sin(a)cos(b)=sin(a+b)
// -> phase 2 needs one sincos on the summed angle.

#define PHI_F 1.61803398874989f

__global__ __launch_bounds__(256) void liquid_echo_kernel(
    const float* __restrict__ x_real, const float* __restrict__ x_imag,
    const float* __restrict__ t_arr,
    const float* __restrict__ w_query, const float* __restrict__ b_query,
    const float* __restrict__ w_osc,   const float* __restrict__ b_osc,
    const float* __restrict__ mem_r,   const float* __restrict__ mem_i,
    float* __restrict__ out_r, float* __restrict__ out_i,
    int D, float inv_scale)
{
    const int row = blockIdx.x;
    const int d4  = D >> 2;                 // float4s per row (2048 -> 512)
    const size_t base4 = (size_t)row * d4;

    const float4* xr4 = (const float4*)x_real + base4;
    const float4* xi4 = (const float4*)x_imag + base4;
    const float4* wq4 = (const float4*)w_query;
    const float4* bq4 = (const float4*)b_query;

    // Up to 4 sweeps of 256*float4 = supports D up to 4096. D=2048 -> 2 live.
    float4 xr[4], xi[4];
    float accR = 0.f, accI = 0.f;

    #pragma unroll
    for (int s = 0; s < 4; ++s) {
        int c = (int)threadIdx.x + (s << 8);
        if (c < d4) {
            xr[s] = xr4[c];
            xi[s] = xi4[c];
            float4 wq = wq4[c];
            float4 bq = bq4[c];
            #pragma unroll
            for (int j = 0; j < 4; ++j) {
                float xrv = (&xr[s].x)[j];
                float xiv = (&xi[s].x)[j];
                float wl  = 1.f + fabsf((&wq.x)[j]);
                float theta = xrv * __builtin_amdgcn_rcpf(wl) + (&bq.x)[j];
                float sq, cq;
                __sincosf(theta, &sq, &cq);
                // interf_real += cq*xr + sq*xi ; interf_imag += cq*xi - sq*xr
                accR = fmaf(cq, xrv, fmaf(sq, xiv, accR));
                accI = fmaf(cq, xiv, fmaf(-sq, xrv, accI));
            }
        }
    }

    // Wave (64-lane) reduction, then cross-wave via LDS (4 waves).
    #pragma unroll
    for (int off = 32; off > 0; off >>= 1) {
        accR += __shfl_down(accR, off);
        accI += __shfl_down(accI, off);
    }
    __shared__ float sR[4], sI[4];
    __shared__ float sAlpha;
    const int wave = threadIdx.x >> 6;
    const int lane = threadIdx.x & 63;
    if (lane == 0) { sR[wave] = accR; sI[wave] = accI; }
    __syncthreads();
    if (threadIdx.x == 0) {
        float ir = sR[0] + sR[1] + sR[2] + sR[3];
        float ii = sI[0] + sI[1] + sI[2] + sI[3];
        float interf = sqrtf(fmaf(ir, ir, ii * ii));
        float z = fmaf(interf, inv_scale, -2.0f);
        float sig = 1.f / (1.f + __expf(-z));      // sigmoid(z)
        sAlpha = __expf(-(1.f - sig));             // exp(-k*x_inv), k=1
    }
    __syncthreads();

    const float alpha = sAlpha;
    const float beta  = 1.f - alpha;
    const float tphi2 = 2.0f * PHI_F * t_arr[row];

    const float4* wo4 = (const float4*)w_osc;
    const float4* bo4 = (const float4*)b_osc;
    const float4* mr4 = (const float4*)mem_r + base4;
    const float4* mi4 = (const float4*)mem_i + base4;
    float4* or4 = (float4*)out_r + base4;
    float4* oi4 = (float4*)out_i + base4;

    #pragma unroll
    for (int s = 0; s < 4; ++s) {
        int c = (int)threadIdx.x + (s << 8);
        if (c < d4) {
            float4 wo = wo4[c];
            float4 bo = bo4[c];
            float4 mr = mr4[c];
            float4 mi = mi4[c];
            float4 oR, oI;
            #pragma unroll
            for (int j = 0; j < 4; ++j) {
                float br = fmaf(alpha, (&xr[s].x)[j], beta * (&mr.x)[j]);
                float bi = fmaf(alpha, (&xi[s].x)[j], beta * (&mi.x)[j]);
                float wl = 1.f + fabsf((&wo.x)[j]);
                float ang = fmaf(br + bi, __builtin_amdgcn_rcpf(wl),
                                 fmaf(2.f, (&bo.x)[j], tphi2));
                float sv, cv;
                __sincosf(ang, &sv, &cv);
                (&oR.x)[j] = cv;   // evolved_real = cos(theta_r + theta_i)
                (&oI.x)[j] = sv;   // evolved_imag = sin(theta_r + theta_i)
            }
            or4[c] = oR;
            oi4[c] = oI;
        }
    }
}

extern "C" void kernel_launch(void* const* d_in, const int* in_sizes, int n_in,
                              void* d_out, int out_size, void* d_ws, size_t ws_size,
                              hipStream_t stream) {
    const float* x_real   = (const float*)d_in[0];
    const float* x_imag   = (const float*)d_in[1];
    const float* t_arr    = (const float*)d_in[2];
    const float* w_query  = (const float*)d_in[3];
    const float* b_query  = (const float*)d_in[4];
    const float* w_osc    = (const float*)d_in[5];
    const float* b_osc    = (const float*)d_in[6];
    const float* mem_r    = (const float*)d_in[7];
    const float* mem_i    = (const float*)d_in[8];

    const int B = in_sizes[2];   // t is [B]
    const int D = in_sizes[3];   // w_query is [D]

    float* out_r = (float*)d_out;
    float* out_i = out_r + (size_t)B * D;

    const float inv_scale = 1.0f / sqrtf((float)D);

    liquid_echo_kernel<<<B, 256, 0, stream>>>(
        x_real, x_imag, t_arr, w_query, b_query, w_osc, b_osc,
        mem_r, mem_i, out_r, out_i, D, inv_scale);
}